// Round 4
// baseline (1830.603 us; speedup 1.0000x reference)
//
#include <hip/hip_runtime.h>

// TemporalCausalMaps on MI355X (gfx950), round 4.
// 2 waves per sample (128-thread blocks) => 16 waves/CU (4/SIMD) instead of 8.
// t-parallel stages split by t-parity across waves; serial GRU recurrence on
// wave l (layer l) using __shfl broadcast of h (no LDS sync inside the loop).

#define NT 128

__device__ __forceinline__ float sigm(float x) { return 1.0f / (1.0f + __expf(-x)); }
__device__ __forceinline__ float tanh_fast(float x) {
  x = fminf(15.0f, fmaxf(-15.0f, x));
  float e = __expf(2.0f * x);
  return (e - 1.0f) / (e + 1.0f);
}
__device__ __forceinline__ float leaky(float x) { return x >= 0.0f ? x : 0.01f * x; }

template <int N4>
__device__ __forceinline__ float dotv(const float* __restrict__ w, const float* h) {
  const float4* w4 = reinterpret_cast<const float4*>(w);
  const float4* h4 = reinterpret_cast<const float4*>(h);
  float acc = 0.0f;
#pragma unroll
  for (int i = 0; i < N4; ++i) {
    float4 a = w4[i], b = h4[i];
    acc = fmaf(a.x, b.x, acc); acc = fmaf(a.y, b.y, acc);
    acc = fmaf(a.z, b.z, acc); acc = fmaf(a.w, b.w, acc);
  }
  return acc;
}

// LDS layout (floats), 16B-aligned offsets. Total 3200 floats = 12.8 KB.
//  s_x  [8][48] @0      s_h  [8][24] @384    s_g  [8][24] @576
//  s_gi [8][72] @768    s_y  [8][24] @1344   s_d1 [8][68] @1536
//  s_d2 [8][68] @2080   s_dec[8][8]  @2624   s_ch [8][64] @2688
__global__ __launch_bounds__(NT, 4) void tcm_kernel(
    const float* __restrict__ z,
    const float* __restrict__ cond_w1, const float* __restrict__ cond_b1,
    const float* __restrict__ cond_w2, const float* __restrict__ cond_b2,
    const float* __restrict__ proj_w, const float* __restrict__ proj_b,
    const float* __restrict__ gpw, const float* __restrict__ gpb,
    const float* __restrict__ gru_wih, const float* __restrict__ gru_whh,
    const float* __restrict__ gru_bih, const float* __restrict__ gru_bhh,
    const float* __restrict__ cm_w1, const float* __restrict__ cm_b1,
    const float* __restrict__ cm_w2, const float* __restrict__ cm_b2,
    const float* __restrict__ cm_w3, const float* __restrict__ cm_b3,
    const int* __restrict__ endw,
    float* __restrict__ out, int Btot) {
  __shared__ __align__(16) float lds[3200];
  float* s_x   = lds;
  float* s_h   = lds + 384;
  float* s_g   = lds + 576;
  float* s_gi  = lds + 768;
  float* s_y   = lds + 1344;
  float* s_d1  = lds + 1536;   // stride 68
  float* s_d2  = lds + 2080;   // stride 68
  float* s_dec = lds + 2624;
  float* s_ch  = lds + 2688;

  const int tid  = threadIdx.x;
  const int lane = tid & 63;
  const int wave = tid >> 6;
  const int b = blockIdx.x;
  const int T = endw[0];

  if (tid < 64) s_dec[tid] = 0.0f;
  __syncthreads();

  // cond ph1 fixed per-thread mapping: (src, k) = tid & 63
  const int c_src = (tid >> 5) & 1;
  const int c_k   = tid & 31;
  const int ck63  = tid & 63;

#pragma unroll 1
  for (int idx = 0; idx < T; ++idx) {
    const int L = idx + 1;
#pragma unroll 1
    for (int n = 0; n < 8; ++n) {
      // ---- stage 1a: z prefix copy (float4), all 128 threads
      {
        const float4* z4 = reinterpret_cast<const float4*>(
            z + ((size_t)n * Btot + b) * 8 * 32);
        float4* x4 = reinterpret_cast<float4*>(s_x);
#pragma unroll 1
        for (int it = tid; it < L * 8; it += NT) {
          int t = it >> 3, q = it & 7;
          x4[t * 12 + q] = z4[t * 8 + q];
        }
      }
      // ---- cond ph1: relu hidden, thread=(src,k), t split by wave parity
      if (idx > 0) {
        int nn = c_src ? (n > 0 ? n - 1 : 0) : n;
        float w1v = cond_w1[nn * 32 + c_k];
        float b1v = cond_b1[nn * 32 + c_k];
#pragma unroll 1
        for (int t = wave; t < L; t += 2) {
          float xv = s_dec[nn * 8 + t];
          s_ch[t * 64 + ck63] = fmaxf(fmaf(xv, w1v, b1v), 0.0f);
        }
      }
      __syncthreads();
      // ---- cond ph2: lanes 0..15 = output col c, t split by wave
      if (lane < 16) {
        int c = lane;
        bool self = c < 8;
        int nn = self ? n : n - 1;
        int e = self ? c : c - 8;
        bool valid = self ? (idx > 0) : (n > 0 && idx > 0);
        float4 W2[8];
        float bb = 0.0f;
        if (valid) {
          const float4* w4 = reinterpret_cast<const float4*>(
              cond_w2 + (size_t)(nn * 8 + e) * 32);
#pragma unroll
          for (int i = 0; i < 8; ++i) W2[i] = w4[i];
          bb = cond_b2[nn * 8 + e];
        }
#pragma unroll 1
        for (int t = wave; t < L; t += 2) {
          float v = 0.0f;
          if (valid && (!self || t < idx)) {
            const float4* c4 = reinterpret_cast<const float4*>(
                s_ch + t * 64 + (self ? 0 : 32));
            float acc = bb;
#pragma unroll
            for (int i = 0; i < 8; ++i) {
              float4 a = W2[i], hh = c4[i];
              acc = fmaf(a.x, hh.x, acc); acc = fmaf(a.y, hh.y, acc);
              acc = fmaf(a.z, hh.z, acc); acc = fmaf(a.w, hh.w, acc);
            }
            v = acc;
          }
          s_x[t * 48 + 32 + c] = v;
        }
      }
      __syncthreads();
      // ---- proj -> leaky: lanes 0..23 = row j, weights hoisted, t split
      if (lane < 24) {
        float4 W[12];
        const float4* w4 = reinterpret_cast<const float4*>(
            proj_w + (size_t)(n * 24 + lane) * 48);
#pragma unroll
        for (int i = 0; i < 12; ++i) W[i] = w4[i];
        float bb = proj_b[n * 24 + lane];
#pragma unroll 1
        for (int t = wave; t < L; t += 2) {
          const float4* x4 = reinterpret_cast<const float4*>(s_x + t * 48);
          float acc = bb;
#pragma unroll
          for (int i = 0; i < 12; ++i) {
            float4 a = W[i], hh = x4[i];
            acc = fmaf(a.x, hh.x, acc); acc = fmaf(a.y, hh.y, acc);
            acc = fmaf(a.z, hh.z, acc); acc = fmaf(a.w, hh.w, acc);
          }
          s_h[t * 24 + lane] = leaky(acc);
        }
      }
      __syncthreads();
      // ---- gru_proj: lanes 0..23 = row j, t split
      if (lane < 24) {
        float4 W[6];
        const float4* w4 = reinterpret_cast<const float4*>(gpw + lane * 24);
#pragma unroll
        for (int i = 0; i < 6; ++i) W[i] = w4[i];
        float bb = gpb[lane];
#pragma unroll 1
        for (int t = wave; t < L; t += 2) {
          const float4* h4 = reinterpret_cast<const float4*>(s_h + t * 24);
          float acc = bb;
#pragma unroll
          for (int i = 0; i < 6; ++i) {
            float4 a = W[i], hh = h4[i];
            acc = fmaf(a.x, hh.x, acc); acc = fmaf(a.y, hh.y, acc);
            acc = fmaf(a.z, hh.z, acc); acc = fmaf(a.w, hh.w, acc);
          }
          s_g[t * 24 + lane] = acc;
        }
      }
      __syncthreads();
      // ---- GRU, 2 layers
      const float* srcp = s_g;
#pragma unroll 1
      for (int l = 0; l < 2; ++l) {
        const int nl = n * 2 + l;
        const float* wih = gru_wih + (size_t)nl * 72 * 24;
        const float* bih = gru_bih + nl * 72;
        // input gates: lane=row (0..63) + rows 64..71 on lanes 0..7; t split
        {
          float4 WA[6], WB[6];
          const float4* wa = reinterpret_cast<const float4*>(wih + (size_t)lane * 24);
          const float4* wb = reinterpret_cast<const float4*>(
              wih + (size_t)(64 + (lane & 7)) * 24);
#pragma unroll
          for (int i = 0; i < 6; ++i) { WA[i] = wa[i]; WB[i] = wb[i]; }
          float bA = bih[lane];
          float bB = bih[64 + (lane & 7)];
#pragma unroll 1
          for (int t = wave; t < L; t += 2) {
            const float4* h4 = reinterpret_cast<const float4*>(srcp + t * 24);
            float accA = bA, accB = bB;
#pragma unroll
            for (int i = 0; i < 6; ++i) {
              float4 hh = h4[i];
              accA = fmaf(WA[i].x, hh.x, accA); accA = fmaf(WA[i].y, hh.y, accA);
              accA = fmaf(WA[i].z, hh.z, accA); accA = fmaf(WA[i].w, hh.w, accA);
              accB = fmaf(WB[i].x, hh.x, accB); accB = fmaf(WB[i].y, hh.y, accB);
              accB = fmaf(WB[i].z, hh.z, accB); accB = fmaf(WB[i].w, hh.w, accB);
            }
            s_gi[t * 72 + lane] = accA;
            if (lane < 8) s_gi[t * 72 + 64 + lane] = accB;
          }
        }
        __syncthreads();
        // recurrence on wave l: h broadcast via __shfl, no LDS sync inside
        if (wave == l) {
          const float* whh = gru_whh + (size_t)nl * 72 * 24;
          const float* bhh = gru_bhh + nl * 72;
          int jm = lane < 24 ? lane : (lane < 48 ? lane - 24 : lane - 48);
          float4 Wr[6], Wz[6], Wn[6];
          {
            const float4* wr4 = reinterpret_cast<const float4*>(whh + jm * 24);
            const float4* wz4 = reinterpret_cast<const float4*>(whh + (24 + jm) * 24);
            const float4* wn4 = reinterpret_cast<const float4*>(whh + (48 + jm) * 24);
#pragma unroll
            for (int i = 0; i < 6; ++i) { Wr[i] = wr4[i]; Wz[i] = wz4[i]; Wn[i] = wn4[i]; }
          }
          float bR = bhh[jm], bZ = bhh[24 + jm], bN = bhh[48 + jm];
          float h = 0.0f;
#pragma unroll 1
          for (int t = 0; t < L; ++t) {
            float gr = bR, gz = bZ, gn = bN;
#pragma unroll
            for (int q = 0; q < 6; ++q) {
              float h0 = __shfl(h, q * 4 + 0);
              float h1 = __shfl(h, q * 4 + 1);
              float h2 = __shfl(h, q * 4 + 2);
              float h3 = __shfl(h, q * 4 + 3);
              gr = fmaf(Wr[q].x, h0, gr); gr = fmaf(Wr[q].y, h1, gr);
              gr = fmaf(Wr[q].z, h2, gr); gr = fmaf(Wr[q].w, h3, gr);
              gz = fmaf(Wz[q].x, h0, gz); gz = fmaf(Wz[q].y, h1, gz);
              gz = fmaf(Wz[q].z, h2, gz); gz = fmaf(Wz[q].w, h3, gz);
              gn = fmaf(Wn[q].x, h0, gn); gn = fmaf(Wn[q].y, h1, gn);
              gn = fmaf(Wn[q].z, h2, gn); gn = fmaf(Wn[q].w, h3, gn);
            }
            const float* gi = s_gi + t * 72;
            float r   = sigm(gi[jm] + gr);
            float zg  = sigm(gi[24 + jm] + gz);
            float nn2 = tanh_fast(gi[48 + jm] + r * gn);
            h = fmaf(zg, h - nn2, nn2);  // (1-z)*n + z*h
            if (lane < 24) s_y[t * 24 + lane] = h;
          }
        }
        __syncthreads();
        srcp = s_y;
      }
      // ---- causal map layer 1: lane=j, weights in regs, t split
      {
        float4 W[6];
        const float4* w4 = reinterpret_cast<const float4*>(
            cm_w1 + (size_t)(n * 64 + lane) * 24);
#pragma unroll
        for (int i = 0; i < 6; ++i) W[i] = w4[i];
        float bb = cm_b1[n * 64 + lane];
#pragma unroll 1
        for (int t = wave; t < L; t += 2) {
          const float4* y4 = reinterpret_cast<const float4*>(s_y + t * 24);
          float acc = bb;
#pragma unroll
          for (int i = 0; i < 6; ++i) {
            float4 a = W[i], hh = y4[i];
            acc = fmaf(a.x, hh.x, acc); acc = fmaf(a.y, hh.y, acc);
            acc = fmaf(a.z, hh.z, acc); acc = fmaf(a.w, hh.w, acc);
          }
          s_d1[t * 68 + lane] = fmaxf(acc, 0.0f);
        }
      }
      __syncthreads();
      // ---- causal map layer 2: lane=j, weights in regs, t split
      {
        float4 W[16];
        const float4* w4 = reinterpret_cast<const float4*>(
            cm_w2 + (size_t)(n * 64 + lane) * 64);
#pragma unroll
        for (int i = 0; i < 16; ++i) W[i] = w4[i];
        float bb = cm_b2[n * 64 + lane];
#pragma unroll 1
        for (int t = wave; t < L; t += 2) {
          const float4* d4 = reinterpret_cast<const float4*>(s_d1 + t * 68);
          float acc = bb;
#pragma unroll
          for (int i = 0; i < 16; ++i) {
            float4 a = W[i], hh = d4[i];
            acc = fmaf(a.x, hh.x, acc); acc = fmaf(a.y, hh.y, acc);
            acc = fmaf(a.z, hh.z, acc); acc = fmaf(a.w, hh.w, acc);
          }
          s_d2[t * 68 + lane] = fmaxf(acc, 0.0f);
        }
      }
      __syncthreads();
      // ---- causal map layer 3 -> decoded + emit (wave0, lane=t)
      if (wave == 0 && lane < L) {
        int t = lane;
        float dv = cm_b3[n] + dotv<16>(cm_w3 + n * 64, s_d2 + t * 68);
        s_dec[n * 8 + t] = dv;
        if (t == idx)
          out[((size_t)b * T + idx) * 8 + n] = dv;
      }
      __syncthreads();
    }
  }
}

extern "C" void kernel_launch(void* const* d_in, const int* in_sizes, int n_in,
                              void* d_out, int out_size, void* d_ws, size_t ws_size,
                              hipStream_t stream) {
  const float* z       = (const float*)d_in[0];
  const float* cond_w1 = (const float*)d_in[1];
  const float* cond_b1 = (const float*)d_in[2];
  const float* cond_w2 = (const float*)d_in[3];
  const float* cond_b2 = (const float*)d_in[4];
  const float* proj_w  = (const float*)d_in[5];
  const float* proj_b  = (const float*)d_in[6];
  const float* gpw     = (const float*)d_in[7];
  const float* gpb     = (const float*)d_in[8];
  const float* gru_wih = (const float*)d_in[9];
  const float* gru_whh = (const float*)d_in[10];
  const float* gru_bih = (const float*)d_in[11];
  const float* gru_bhh = (const float*)d_in[12];
  const float* cm_w1   = (const float*)d_in[13];
  const float* cm_b1   = (const float*)d_in[14];
  const float* cm_w2   = (const float*)d_in[15];
  const float* cm_b2   = (const float*)d_in[16];
  const float* cm_w3   = (const float*)d_in[17];
  const float* cm_b3   = (const float*)d_in[18];
  const int*   endw    = (const int*)d_in[19];
  float* out = (float*)d_out;

  int Btot = in_sizes[0] / (8 * 8 * 32);  // z: [8, B, 8, 32]

  tcm_kernel<<<Btot, NT, 0, stream>>>(
      z, cond_w1, cond_b1, cond_w2, cond_b2, proj_w, proj_b, gpw, gpb,
      gru_wih, gru_whh, gru_bih, gru_bhh, cm_w1, cm_b1, cm_w2, cm_b2,
      cm_w3, cm_b3, endw, out, Btot);
}